// Round 4
// baseline (9664.102 us; speedup 1.0000x reference)
//
#include <hip/hip_runtime.h>
#include <hip/hip_bf16.h>

// Problem constants
#define BB 128   // batch
#define TT 1024  // timesteps
#define HH 512   // hidden
#define VV 256   // vocab
#define NBLK 128 // 64 stage1 + 64 stage2 blocks (32 per batch-half each) — proven co-resident

typedef __attribute__((ext_vector_type(8))) short short8;   // 8 x bf16
typedef __attribute__((ext_vector_type(4))) float floatx4;  // MFMA acc

__device__ __forceinline__ floatx4 mfma16(short8 a, short8 b, floatx4 c) {
    return __builtin_amdgcn_mfma_f32_16x16x32_bf16(a, b, c, 0, 0, 0);
}
__device__ __forceinline__ float sigm(float x) { return 1.0f / (1.0f + __expf(-x)); }
__device__ __forceinline__ float tanh_fast(float x) {
    return 2.0f / (1.0f + __expf(-2.0f * x)) - 1.0f;
}
__device__ __forceinline__ void vmcnt0() {
    asm volatile("s_waitcnt vmcnt(0)" ::: "memory");
}
// waitcnt + scheduler fence: MFMAs consuming asm-load results must not hoist above.
__device__ __forceinline__ void vm_fence() {
    asm volatile("s_waitcnt vmcnt(0)" ::: "memory");
    __builtin_amdgcn_sched_barrier(0);
}
// Relaxed agent-scope ops: MALL-coherent, NO cache writeback/invalidate.
__device__ __forceinline__ unsigned ald32(const unsigned* p) {
    return __hip_atomic_load(p, __ATOMIC_RELAXED, __HIP_MEMORY_SCOPE_AGENT);
}
__device__ __forceinline__ void ast32(unsigned* p, unsigned v) {
    __hip_atomic_store(p, v, __ATOMIC_RELAXED, __HIP_MEMORY_SCOPE_AGENT);
}
// MALL-path 16B load (bypasses local caches) for reused ring addresses.
__device__ __forceinline__ short8 ld16_sc1(const __hip_bfloat16* p) {
    short8 v;
    asm volatile("global_load_dwordx4 %0, %1, off sc1" : "=v"(v) : "v"(p));
    return v;
}
// Poll one cumulative counter until >= tgt. All lanes load the SAME dword
// (coalescer merges to one request; value is wave-uniform so the branch is too).
// Busy-spin first (min discovery latency), then throttle.
__device__ __forceinline__ void pollc(const unsigned* c, unsigned tgt) {
    int it = 0;
    for (;;) {
        unsigned v = ald32(c);
        if (v >= tgt) return;
        if (++it > 64) __builtin_amdgcn_s_sleep(1);
    }
}

// One-shot canonicalization: fp32 weights -> bf16 ws copies; bias pre-sums; x transpose.
__global__ __launch_bounds__(256) void canon(
    const float* __restrict__ x,
    const float* __restrict__ Whh1, const float* __restrict__ Wih2,
    const float* __restrict__ Whh2, const float* __restrict__ Wlin,
    const float* __restrict__ bih1, const float* __restrict__ bhh1,
    const float* __restrict__ bih2, const float* __restrict__ bhh2,
    __hip_bfloat16* __restrict__ Whh1c, __hip_bfloat16* __restrict__ Wih2c,
    __hip_bfloat16* __restrict__ Whh2c, __hip_bfloat16* __restrict__ Wlinc,
    float* __restrict__ bsum1, float* __restrict__ bsum2,
    float* __restrict__ xT)
{
    const int tid = blockIdx.x * 256 + threadIdx.x;
    const int np  = gridDim.x * 256;
    for (int i = tid; i < 2048 * 512; i += np) {
        Whh1c[i] = __float2bfloat16(Whh1[i]);
        Wih2c[i] = __float2bfloat16(Wih2[i]);
        Whh2c[i] = __float2bfloat16(Whh2[i]);
    }
    for (int i = tid; i < 256 * 512; i += np) Wlinc[i] = __float2bfloat16(Wlin[i]);
    for (int i = tid; i < 2048; i += np) {
        bsum1[i] = bih1[i] + bhh1[i];
        bsum2[i] = bih2[i] + bhh2[i];
    }
    for (int i = tid; i < BB * TT; i += np) {
        int b = i >> 10, t = i & 1023;
        xT[t * BB + b] = x[i];
    }
}

// Persistent dataflow LSTM. 4 independent groups: {stage1,stage2} x {batch half}.
// Sync: cumulative per-step counters done[grp][t] (u32, no reuse => no reset races).
// Publish: per-wave vmcnt0 drain -> LDS wave-counter -> last wave does ONE global
// atomicAdd(+1). Readiness = counter==32 at a single address (32nd RMW at the MALL
// slice IS the event; no 32-store line reassembly). Poll = merged same-address load.
// NO __syncthreads in the steady-state loop; every wave polls independently.
// h1: full array (slot t+1 = h1(t)), plain cached loads. h2: 4-ring, sc1 loads.
__global__ __launch_bounds__(256, 1) void lstm_persist(
    const float* __restrict__ xT,              // [T][B] fp32
    const float* __restrict__ Wih1,            // [2048] fp32 (IN=1)
    const __hip_bfloat16* __restrict__ Whh1c,  // [2048,512] bf16
    const float* __restrict__ bsum1,           // [2048]
    const __hip_bfloat16* __restrict__ Wih2c,  // [2048,512] bf16
    const __hip_bfloat16* __restrict__ Whh2c,  // [2048,512] bf16
    const float* __restrict__ bsum2,           // [2048]
    unsigned* __restrict__ done,               // [4][2048] u32 cumulative counters
    unsigned* __restrict__ h2ring,             // [4][B*H/2] u32
    unsigned* __restrict__ h1all,              // [1025][B*H/2] u32
    __hip_bfloat16* __restrict__ h2slots)      // d_out as bf16 slots [B][T][H]
{
    extern __shared__ __hip_bfloat16 lds[];    // stage1: 64 KB; stage2: 128 KB
    __shared__ unsigned cnt[16];               // per-step wave-completion counters

    const int bid   = blockIdx.x;
    const int stage = bid >> 6;                // 0: layer1, 1: layer2
    const int half  = (bid >> 5) & 1;          // batch half
    const int lb    = bid & 31;
    const int j0    = lb * 16;                 // h-unit tile
    const int b0    = half * 64;               // batch tile
    const int w     = threadIdx.x >> 6;
    const int lane  = threadIdx.x & 63;
    const int q     = lane >> 4, ln = lane & 15;
    const int r0    = b0 + w * 16;

    unsigned* done1h = done + half * 2048;            // stage1 counters, this half
    unsigned* done2h = done + 4096 + half * 2048;     // stage2 counters, this half
    unsigned* mydone = (stage == 0) ? done1h : done2h;

    // ---- stage weights into LDS, fragment-permuted (once) ----
    {
        const __hip_bfloat16* S0 = (stage == 0) ? Whh1c : Wih2c;
        for (int idx = threadIdx.x; idx < 4096; idx += 256) {
            const int g = idx >> 10, kk = (idx >> 6) & 15, l = idx & 63;
            const int lnt = l & 15, qt = l >> 4;
            const size_t src = (size_t)(g * 512 + j0 + lnt) * 512 + kk * 32 + qt * 8;
            *(float4*)(lds + idx * 8) = *(const float4*)(S0 + src);
            if (stage == 1)
                *(float4*)(lds + 32768 + idx * 8) = *(const float4*)(Whh2c + src);
        }
    }
    if (threadIdx.x < 16) cnt[threadIdx.x] = 0;
    __syncthreads();   // weights + counters ready; last __syncthreads in this kernel

    // per-thread step-invariant epilogue constants
    float wv[4], bs[4];
    #pragma unroll
    for (int g = 0; g < 4; ++g) {
        const int j = g * 512 + j0 + ln;
        if (stage == 0) { wv[g] = Wih1[j]; bs[g] = bsum1[j]; }
        else            { wv[g] = 0.0f;    bs[g] = bsum2[j]; }
    }
    float cre[4] = {0.0f, 0.0f, 0.0f, 0.0f};   // register-resident cell state

    const __hip_bfloat16* h1bf = (const __hip_bfloat16*)h1all;
    const int aoff = (r0 + ln) * HH + q * 8;          // A-frag element offset
    const int jc   = j0 + (ln & ~1);                  // pack: even column of pair
    const int rA   = (ln & 1) ? 2 : 0;
    const int bA   = r0 + q * 4 + rA;
    const int o0   = (bA * HH + jc) >> 1;
    const int o1   = ((bA + 1) * HH + jc) >> 1;

    for (int t = 0; t < TT; ++t) {
        floatx4 acc[4];
        #pragma unroll
        for (int g = 0; g < 4; ++g) acc[g] = floatx4{0, 0, 0, 0};
        unsigned pk[4];

        if (stage == 0) {
            if (t > 0) pollc(done1h + (t - 1), 32u);   // own group done step t-1
            __builtin_amdgcn_sched_barrier(0);
            // h1(t-1) = slot t, plain cached dwordx4 loads (unique addresses)
            const __hip_bfloat16* hA = h1bf + (size_t)t * 65536;
            float4 xv4 = *(const float4*)(xT + t * BB + r0 + q * 4);
            short8 A0[16];
            #pragma unroll
            for (int kk = 0; kk < 16; ++kk)
                A0[kk] = *(const short8*)(hA + aoff + kk * 32);
            #pragma unroll
            for (int kk = 0; kk < 16; ++kk) {
                #pragma unroll
                for (int g = 0; g < 4; ++g)
                    acc[g] = mfma16(A0[kk],
                        *(const short8*)(lds + ((g * 16 + kk) * 64 + lane) * 8), acc[g]);
            }
            #pragma unroll
            for (int reg = 0; reg < 4; ++reg) {
                const float xv = ((const float*)&xv4)[reg];
                float gi = acc[0][reg] + xv * wv[0] + bs[0];
                float gf = acc[1][reg] + xv * wv[1] + bs[1];
                float gg = acc[2][reg] + xv * wv[2] + bs[2];
                float go = acc[3][reg] + xv * wv[3] + bs[3];
                float cn = sigm(gf) * cre[reg] + sigm(gi) * tanh_fast(gg);
                cre[reg] = cn;
                float hn = sigm(go) * tanh_fast(cn);
                __hip_bfloat16 hb = __float2bfloat16(hn);
                unsigned short us; __builtin_memcpy(&us, &hb, 2);
                unsigned mine = us;
                unsigned other = (unsigned)__shfl_xor((int)mine, 1, 64);
                pk[reg] = (ln & 1) ? ((other & 0xffffu) | (mine << 16))
                                   : ((mine & 0xffffu) | (other << 16));
            }
            unsigned* dst = h1all + (size_t)(t + 1) * 32768;    // h1(t) -> slot t+1
            ast32(dst + o0, pk[rA]);
            ast32(dst + o1, pk[rA + 1]);
            // publish: drain own-wave stores, last wave of block bumps the counter
            vmcnt0();
            if (lane == 0) {
                unsigned old = atomicAdd(&cnt[t & 15], 1u);     // LDS, block-local
                if (old == 3) {
                    cnt[(t + 8) & 15] = 0;                      // recycle (skew <= 1)
                    atomicAdd(mydone + t, 1u);                  // 32nd add == ready
                }
            }
        } else {
            // stage2 step t: h2(t) = f(h1(t) [slot t+1], h2(t-1) [ring t&3])
            pollc(done1h + t, 32u);                     // h1(t) ready (S1 runs ahead)
            __builtin_amdgcn_sched_barrier(0);
            // issue h1 loads immediately; their latency hides under the binding wait
            const __hip_bfloat16* hA = h1bf + (size_t)(t + 1) * 65536;
            short8 A0[16];
            #pragma unroll
            for (int kk = 0; kk < 16; ++kk)
                A0[kk] = *(const short8*)(hA + aoff + kk * 32);
            if (t > 0) pollc(done2h + (t - 1), 32u);    // own group done t-1 (binding)
            __builtin_amdgcn_sched_barrier(0);
            const __hip_bfloat16* hB =
                (const __hip_bfloat16*)h2ring + (size_t)(t & 3) * 65536;
            short8 A1[16];
            #pragma unroll
            for (int kk = 0; kk < 16; ++kk) A1[kk] = ld16_sc1(hB + aoff + kk * 32);
            vm_fence();   // all A-operands resident
            #pragma unroll
            for (int kk = 0; kk < 16; ++kk) {
                #pragma unroll
                for (int g = 0; g < 4; ++g)
                    acc[g] = mfma16(A0[kk],
                        *(const short8*)(lds + ((g * 16 + kk) * 64 + lane) * 8), acc[g]);
            }
            #pragma unroll
            for (int kk = 0; kk < 16; ++kk) {
                #pragma unroll
                for (int g = 0; g < 4; ++g)
                    acc[g] = mfma16(A1[kk],
                        *(const short8*)(lds + 32768 + ((g * 16 + kk) * 64 + lane) * 8), acc[g]);
            }
            #pragma unroll
            for (int reg = 0; reg < 4; ++reg) {
                float gi = acc[0][reg] + bs[0];
                float gf = acc[1][reg] + bs[1];
                float gg = acc[2][reg] + bs[2];
                float go = acc[3][reg] + bs[3];
                float cn = sigm(gf) * cre[reg] + sigm(gi) * tanh_fast(gg);
                cre[reg] = cn;
                float hn = sigm(go) * tanh_fast(cn);
                __hip_bfloat16 hb = __float2bfloat16(hn);
                unsigned short us; __builtin_memcpy(&us, &hb, 2);
                unsigned mine = us;
                unsigned other = (unsigned)__shfl_xor((int)mine, 1, 64);
                pk[reg] = (ln & 1) ? ((other & 0xffffu) | (mine << 16))
                                   : ((mine & 0xffffu) | (other << 16));
            }
            // recurrence-critical ring stores only, then drain + publish
            unsigned* dst = h2ring + (size_t)((t + 1) & 3) * 32768; // h2(t)
            ast32(dst + o0, pk[rA]);
            ast32(dst + o1, pk[rA + 1]);
            vmcnt0();
            if (lane == 0) {
                unsigned old = atomicAdd(&cnt[t & 15], 1u);
                if (old == 3) {
                    cnt[(t + 8) & 15] = 0;
                    atomicAdd(mydone + t, 1u);
                }
            }
            // output stores post-publish: fire-and-forget (next iter's vmcnt0 /
            // kernel-end flush drains them; unique addresses, plain cached)
            unsigned* outs = (unsigned*)h2slots;
            outs[(((size_t)bA * TT + t) * HH + jc) >> 1]       = pk[rA];
            outs[(((size_t)(bA + 1) * TT + t) * HH + jc) >> 1] = pk[rA + 1];
        }
    }
}

// In-place linear+softmax over all T*B rows (slot r: 512 bf16 -> 256 fp32).
__global__ __launch_bounds__(256) void lin_softmax(
    const __hip_bfloat16* __restrict__ Wlinc,  // [256,512] bf16
    const float* __restrict__ blin,            // [256] fp32
    float* out)                                // d_out; aliases the bf16 slots
{
    const __hip_bfloat16* slots = (const __hip_bfloat16*)out;
    const int w = threadIdx.x >> 6;
    const int lane = threadIdx.x & 63;
    const int q = lane >> 4, ln = lane & 15;
    const int r0 = blockIdx.x * 64 + w * 16;

    floatx4 acc[16];
    #pragma unroll
    for (int n = 0; n < 16; ++n) acc[n] = floatx4{0, 0, 0, 0};

    const size_t arow = (size_t)(r0 + ln) * HH + q * 8;
    #pragma unroll 4
    for (int kk = 0; kk < 16; ++kk) {
        short8 a = *(const short8*)(slots + arow + kk * 32);
        #pragma unroll
        for (int n = 0; n < 16; ++n) {
            short8 bf = *(const short8*)(Wlinc + (n * 16 + ln) * HH + kk * 32 + q * 8);
            acc[n] = mfma16(a, bf, acc[n]);
        }
    }

    float bl[16];
    #pragma unroll
    for (int n = 0; n < 16; ++n) bl[n] = blin[n * 16 + ln];

    #pragma unroll
    for (int reg = 0; reg < 4; ++reg) {
        float v[16];
        float mx = -3.4e38f;
        #pragma unroll
        for (int n = 0; n < 16; ++n) {
            v[n] = acc[n][reg] + bl[n];
            mx = fmaxf(mx, v[n]);
        }
        #pragma unroll
        for (int m = 1; m < 16; m <<= 1) mx = fmaxf(mx, __shfl_xor(mx, m));
        float sum = 0.0f;
        #pragma unroll
        for (int n = 0; n < 16; ++n) { v[n] = __expf(v[n] - mx); sum += v[n]; }
        #pragma unroll
        for (int m = 1; m < 16; m <<= 1) sum += __shfl_xor(sum, m);
        const float inv = 1.0f / sum;

        const int r = r0 + q * 4 + reg;        // r = b*T + t
        #pragma unroll
        for (int n = 0; n < 16; ++n)
            out[(size_t)r * VV + n * 16 + ln] = v[n] * inv;
    }
}

extern "C" void kernel_launch(void* const* d_in, const int* in_sizes, int n_in,
                              void* d_out, int out_size, void* d_ws, size_t ws_size,
                              hipStream_t stream)
{
    const float* x     = (const float*)d_in[0];
    const float* W_ih1 = (const float*)d_in[1];
    const float* W_hh1 = (const float*)d_in[2];
    const float* b_ih1 = (const float*)d_in[3];
    const float* b_hh1 = (const float*)d_in[4];
    const float* W_ih2 = (const float*)d_in[5];
    const float* W_hh2 = (const float*)d_in[6];
    const float* b_ih2 = (const float*)d_in[7];
    const float* b_hh2 = (const float*)d_in[8];
    const float* W_lin = (const float*)d_in[9];
    const float* b_lin = (const float*)d_in[10];

    char* p = (char*)d_ws;
    unsigned* done   = (unsigned*)p;   p += 32768;                    // 4 x 2048 u32
    unsigned* h2ring = (unsigned*)p;   p += (size_t)4 * 131072;       // 512 KB
    unsigned* h1all  = (unsigned*)p;   p += (size_t)1025 * 131072;    // 128.1 MB
    const size_t zbytes = 32768 + (size_t)4 * 131072 + 131072;        // done+ring+slot0
    float* bsum1 = (float*)p;          p += 2048 * 4;
    float* bsum2 = (float*)p;          p += 2048 * 4;
    float* xT    = (float*)p;          p += (size_t)BB * TT * 4;
    __hip_bfloat16* Whh1c = (__hip_bfloat16*)p; p += (size_t)2048 * 512 * 2;
    __hip_bfloat16* Wih2c = (__hip_bfloat16*)p; p += (size_t)2048 * 512 * 2;
    __hip_bfloat16* Whh2c = (__hip_bfloat16*)p; p += (size_t)2048 * 512 * 2;
    __hip_bfloat16* Wlinc = (__hip_bfloat16*)p; p += (size_t)256 * 512 * 2;
    // total ws use ~141.7 MB (proven available)

    hipMemsetAsync(d_ws, 0, zbytes, stream);   // counters + h2 ring + h1 slot 0

    canon<<<dim3(512), dim3(256), 0, stream>>>(
        x, W_hh1, W_ih2, W_hh2, W_lin, b_ih1, b_hh1, b_ih2, b_hh2,
        Whh1c, Wih2c, Whh2c, Wlinc, bsum1, bsum2, xT);

    const int smem_bytes = 131072;   // 128 KB dynamic LDS
    (void)hipFuncSetAttribute((const void*)lstm_persist,
                              hipFuncAttributeMaxDynamicSharedMemorySize, smem_bytes);

    lstm_persist<<<dim3(NBLK), dim3(256), smem_bytes, stream>>>(
        xT, W_ih1, Whh1c, bsum1, Wih2c, Whh2c, bsum2,
        done, h2ring, h1all, (__hip_bfloat16*)d_out);

    lin_softmax<<<dim3((TT * BB) / 64), dim3(256), 0, stream>>>(
        Wlinc, b_lin, (float*)d_out);
}

// Round 5
// 9232.893 us; speedup vs baseline: 1.0467x; 1.0467x over previous
//
#include <hip/hip_runtime.h>
#include <hip/hip_bf16.h>

// Problem constants
#define BB 128   // batch
#define TT 1024  // timesteps
#define HH 512   // hidden
#define VV 256   // vocab
#define NBLK 128 // 64 stage1 + 64 stage2 blocks (32 per batch-half each) — proven co-resident

typedef __attribute__((ext_vector_type(8))) short short8;   // 8 x bf16
typedef __attribute__((ext_vector_type(4))) float floatx4;  // MFMA acc

__device__ __forceinline__ floatx4 mfma16(short8 a, short8 b, floatx4 c) {
    return __builtin_amdgcn_mfma_f32_16x16x32_bf16(a, b, c, 0, 0, 0);
}
__device__ __forceinline__ float sigm(float x) { return 1.0f / (1.0f + __expf(-x)); }
__device__ __forceinline__ float tanh_fast(float x) {
    return 2.0f / (1.0f + __expf(-2.0f * x)) - 1.0f;
}
__device__ __forceinline__ void vmcnt0() {
    asm volatile("s_waitcnt vmcnt(0)" ::: "memory");
}
// Relaxed agent-scope ops: MALL-coherent, NO cache writeback/invalidate.
__device__ __forceinline__ unsigned ald32(const unsigned* p) {
    return __hip_atomic_load(p, __ATOMIC_RELAXED, __HIP_MEMORY_SCOPE_AGENT);
}
__device__ __forceinline__ void ast32(unsigned* p, unsigned v) {
    __hip_atomic_store(p, v, __ATOMIC_RELAXED, __HIP_MEMORY_SCOPE_AGENT);
}

// Spin until all 32 flags of `line` >= tgt (lanes 0-31 poll; coalesced 1-line load).
// Called by wave 0 only.
__device__ __forceinline__ void poll1(const unsigned* line, unsigned tgt, int lane) {
    for (;;) {
        unsigned v = tgt;
        if (lane < 32) v = ald32(line + lane);
        if (__all((int)(v >= tgt))) return;
        __builtin_amdgcn_s_sleep(1);
    }
}
// Dual poll: lanes 0-31 check lineA>=tA, lanes 32-63 check lineB>=tB. Wave 0 only.
__device__ __forceinline__ void poll2(const unsigned* lineA, unsigned tA,
                                      const unsigned* lineB, unsigned tB, int lane) {
    const unsigned* p = (lane < 32) ? (lineA + lane) : (lineB + (lane - 32));
    const unsigned tgt = (lane < 32) ? tA : tB;
    for (;;) {
        unsigned v = ald32(p);
        if (__all((int)(v >= tgt))) return;
        __builtin_amdgcn_s_sleep(1);
    }
}

// One-shot canonicalization: fp32 weights -> bf16 ws copies; bias pre-sums; x transpose.
__global__ __launch_bounds__(256) void canon(
    const float* __restrict__ x,
    const float* __restrict__ Whh1, const float* __restrict__ Wih2,
    const float* __restrict__ Whh2, const float* __restrict__ Wlin,
    const float* __restrict__ bih1, const float* __restrict__ bhh1,
    const float* __restrict__ bih2, const float* __restrict__ bhh2,
    __hip_bfloat16* __restrict__ Whh1c, __hip_bfloat16* __restrict__ Wih2c,
    __hip_bfloat16* __restrict__ Whh2c, __hip_bfloat16* __restrict__ Wlinc,
    float* __restrict__ bsum1, float* __restrict__ bsum2,
    float* __restrict__ xT)
{
    const int tid = blockIdx.x * 256 + threadIdx.x;
    const int np  = gridDim.x * 256;
    for (int i = tid; i < 2048 * 512; i += np) {
        Whh1c[i] = __float2bfloat16(Whh1[i]);
        Wih2c[i] = __float2bfloat16(Wih2[i]);
        Whh2c[i] = __float2bfloat16(Whh2[i]);
    }
    for (int i = tid; i < 256 * 512; i += np) Wlinc[i] = __float2bfloat16(Wlin[i]);
    for (int i = tid; i < 2048; i += np) {
        bsum1[i] = bih1[i] + bhh1[i];
        bsum2[i] = bih2[i] + bhh2[i];
    }
    for (int i = tid; i < BB * TT; i += np) {
        int b = i >> 10, t = i & 1023;
        xT[t * BB + b] = x[i];
    }
}

// Persistent dataflow LSTM. 4 independent groups: {stage1,stage2} x {batch half}.
// Sync (R3-proven): 4 flag lines spread 4 KB apart; flags[line*1024+lb] = completed
// steps of block lb. Wave 0 is the sole poller; release + publish via barriers;
// thread 0 stores the flag. h1: full array (slot t+1 = h1(t)), agent stores, plain
// cached loads (unique addresses). h2: NO ring — d_out's bf16 slot array [B][T][H]
// is itself a unique-address h2 history: S2 agent-stores h2(t) there once
// (pre-publish) and plain-loads h2(t-1) from it (L2-shared among same-XCD blocks).
// At t=0 the h2(-1) contribution is exactly zero -> A1 loads/MFMAs skipped.
__global__ __launch_bounds__(256, 1) void lstm_persist(
    const float* __restrict__ xT,              // [T][B] fp32
    const float* __restrict__ Wih1,            // [2048] fp32 (IN=1)
    const __hip_bfloat16* __restrict__ Whh1c,  // [2048,512] bf16
    const float* __restrict__ bsum1,           // [2048]
    const __hip_bfloat16* __restrict__ Wih2c,  // [2048,512] bf16
    const __hip_bfloat16* __restrict__ Whh2c,  // [2048,512] bf16
    const float* __restrict__ bsum2,           // [2048]
    unsigned* __restrict__ flags,              // [4][1024] u32, 4KB-strided lines
    unsigned* __restrict__ h1all,              // [1025][B*H/2] u32
    __hip_bfloat16* __restrict__ h2slots)      // d_out as bf16 slots [B][T][H]
{
    extern __shared__ __hip_bfloat16 lds[];    // stage1: 64 KB; stage2: 128 KB

    const int bid   = blockIdx.x;
    const int stage = bid >> 6;                // 0: layer1, 1: layer2
    const int half  = (bid >> 5) & 1;          // batch half
    const int lb    = bid & 31;
    const int j0    = lb * 16;                 // h-unit tile
    const int b0    = half * 64;               // batch tile
    const int w     = threadIdx.x >> 6;
    const int lane  = threadIdx.x & 63;
    const int q     = lane >> 4, ln = lane & 15;
    const int r0    = b0 + w * 16;

    unsigned* myflag       = flags + (stage * 2 + half) * 1024 + lb;
    const unsigned* line1  = flags + half * 1024;          // stage1 flags, this half
    const unsigned* line2  = flags + (2 + half) * 1024;    // stage2 flags, this half

    // ---- stage weights into LDS, fragment-permuted (once) ----
    {
        const __hip_bfloat16* S0 = (stage == 0) ? Whh1c : Wih2c;
        for (int idx = threadIdx.x; idx < 4096; idx += 256) {
            const int g = idx >> 10, kk = (idx >> 6) & 15, l = idx & 63;
            const int lnt = l & 15, qt = l >> 4;
            const size_t src = (size_t)(g * 512 + j0 + lnt) * 512 + kk * 32 + qt * 8;
            *(float4*)(lds + idx * 8) = *(const float4*)(S0 + src);
            if (stage == 1)
                *(float4*)(lds + 32768 + idx * 8) = *(const float4*)(Whh2c + src);
        }
    }
    __syncthreads();   // weights ready

    // per-thread step-invariant epilogue constants
    float wv[4], bs[4];
    #pragma unroll
    for (int g = 0; g < 4; ++g) {
        const int j = g * 512 + j0 + ln;
        if (stage == 0) { wv[g] = Wih1[j]; bs[g] = bsum1[j]; }
        else            { wv[g] = 0.0f;    bs[g] = bsum2[j]; }
    }
    float cre[4] = {0.0f, 0.0f, 0.0f, 0.0f};   // register-resident cell state

    const __hip_bfloat16* h1bf = (const __hip_bfloat16*)h1all;
    const __hip_bfloat16* h2bf = (const __hip_bfloat16*)h2slots;
    const int aoff = (r0 + ln) * HH + q * 8;          // A-frag offset (h1 layout)
    const size_t a2off = (size_t)(r0 + ln) * TT * HH + q * 8;  // h2slots layout
    const int jc   = j0 + (ln & ~1);                  // pack: even column of pair
    const int rA   = (ln & 1) ? 2 : 0;
    const int bA   = r0 + q * 4 + rA;
    const int o0   = (bA * HH + jc) >> 1;
    const int o1   = ((bA + 1) * HH + jc) >> 1;

    for (int t = 0; t < TT; ++t) {
        floatx4 acc[4];
        #pragma unroll
        for (int g = 0; g < 4; ++g) acc[g] = floatx4{0, 0, 0, 0};
        unsigned pk[4];

        if (stage == 0) {
            if (w == 0 && t > 0) poll1(line1, (unsigned)t, lane);  // own group done t-1
            __syncthreads();                                       // release all waves
            // h1(t-1) = slot t, plain cached dwordx4 loads (unique addresses)
            const __hip_bfloat16* hA = h1bf + (size_t)t * 65536;
            float4 xv4 = *(const float4*)(xT + t * BB + r0 + q * 4);
            short8 A0[16];
            #pragma unroll
            for (int kk = 0; kk < 16; ++kk)
                A0[kk] = *(const short8*)(hA + aoff + kk * 32);
            #pragma unroll
            for (int kk = 0; kk < 16; ++kk) {
                #pragma unroll
                for (int g = 0; g < 4; ++g)
                    acc[g] = mfma16(A0[kk],
                        *(const short8*)(lds + ((g * 16 + kk) * 64 + lane) * 8), acc[g]);
            }
            #pragma unroll
            for (int reg = 0; reg < 4; ++reg) {
                const float xv = ((const float*)&xv4)[reg];
                float gi = acc[0][reg] + xv * wv[0] + bs[0];
                float gf = acc[1][reg] + xv * wv[1] + bs[1];
                float gg = acc[2][reg] + xv * wv[2] + bs[2];
                float go = acc[3][reg] + xv * wv[3] + bs[3];
                float cn = sigm(gf) * cre[reg] + sigm(gi) * tanh_fast(gg);
                cre[reg] = cn;
                float hn = sigm(go) * tanh_fast(cn);
                __hip_bfloat16 hb = __float2bfloat16(hn);
                unsigned short us; __builtin_memcpy(&us, &hb, 2);
                unsigned mine = us;
                unsigned other = (unsigned)__shfl_xor((int)mine, 1, 64);
                pk[reg] = (ln & 1) ? ((other & 0xffffu) | (mine << 16))
                                   : ((mine & 0xffffu) | (other << 16));
            }
            unsigned* dst = h1all + (size_t)(t + 1) * 32768;    // h1(t) -> slot t+1
            ast32(dst + o0, pk[rA]);
            ast32(dst + o1, pk[rA + 1]);
        } else {
            // stage2 step t: h2(t) = f(h1(t) [slot t+1], h2(t-1) [h2slots at t-1])
            if (w == 0) poll2(line1, (unsigned)(t + 1), line2, (unsigned)t, lane);
            __syncthreads();                                       // release all waves
            // A1 = h2(t-1) from d_out history (plain cached; unique addresses;
            // same-XCD S2 blocks share the L2 fills). A0 = h1(t) from L2/MALL.
            short8 A1[16];
            if (t > 0) {
                const __hip_bfloat16* hB = h2bf + (size_t)(t - 1) * HH;
                #pragma unroll
                for (int kk = 0; kk < 16; ++kk)
                    A1[kk] = *(const short8*)(hB + a2off + kk * 32);
            }
            const __hip_bfloat16* hA = h1bf + (size_t)(t + 1) * 65536;
            short8 A0[16];
            #pragma unroll
            for (int kk = 0; kk < 16; ++kk)
                A0[kk] = *(const short8*)(hA + aoff + kk * 32);
            #pragma unroll
            for (int kk = 0; kk < 16; ++kk) {
                #pragma unroll
                for (int g = 0; g < 4; ++g)
                    acc[g] = mfma16(A0[kk],
                        *(const short8*)(lds + ((g * 16 + kk) * 64 + lane) * 8), acc[g]);
            }
            if (t > 0) {
                #pragma unroll
                for (int kk = 0; kk < 16; ++kk) {
                    #pragma unroll
                    for (int g = 0; g < 4; ++g)
                        acc[g] = mfma16(A1[kk],
                            *(const short8*)(lds + 32768 + ((g * 16 + kk) * 64 + lane) * 8), acc[g]);
                }
            }
            #pragma unroll
            for (int reg = 0; reg < 4; ++reg) {
                float gi = acc[0][reg] + bs[0];
                float gf = acc[1][reg] + bs[1];
                float gg = acc[2][reg] + bs[2];
                float go = acc[3][reg] + bs[3];
                float cn = sigm(gf) * cre[reg] + sigm(gi) * tanh_fast(gg);
                cre[reg] = cn;
                float hn = sigm(go) * tanh_fast(cn);
                __hip_bfloat16 hb = __float2bfloat16(hn);
                unsigned short us; __builtin_memcpy(&us, &hb, 2);
                unsigned mine = us;
                unsigned other = (unsigned)__shfl_xor((int)mine, 1, 64);
                pk[reg] = (ln & 1) ? ((other & 0xffffu) | (mine << 16))
                                   : ((mine & 0xffffu) | (other << 16));
            }
            // single store set: h2(t) -> d_out slots (recurrence + output in one)
            unsigned* outs = (unsigned*)h2slots;
            ast32(&outs[(((size_t)bA * TT + t) * HH + jc) >> 1],       pk[rA]);
            ast32(&outs[(((size_t)(bA + 1) * TT + t) * HH + jc) >> 1], pk[rA + 1]);
        }

        // ---- publish: every wave drains its stores, barrier, one flag store ----
        vmcnt0();
        __syncthreads();
        if (threadIdx.x == 0) ast32(myflag, (unsigned)(t + 1));
    }
}

// In-place linear+softmax over all T*B rows (slot r: 512 bf16 -> 256 fp32).
__global__ __launch_bounds__(256) void lin_softmax(
    const __hip_bfloat16* __restrict__ Wlinc,  // [256,512] bf16
    const float* __restrict__ blin,            // [256] fp32
    float* out)                                // d_out; aliases the bf16 slots
{
    const __hip_bfloat16* slots = (const __hip_bfloat16*)out;
    const int w = threadIdx.x >> 6;
    const int lane = threadIdx.x & 63;
    const int q = lane >> 4, ln = lane & 15;
    const int r0 = blockIdx.x * 64 + w * 16;

    floatx4 acc[16];
    #pragma unroll
    for (int n = 0; n < 16; ++n) acc[n] = floatx4{0, 0, 0, 0};

    const size_t arow = (size_t)(r0 + ln) * HH + q * 8;
    #pragma unroll 4
    for (int kk = 0; kk < 16; ++kk) {
        short8 a = *(const short8*)(slots + arow + kk * 32);
        #pragma unroll
        for (int n = 0; n < 16; ++n) {
            short8 bf = *(const short8*)(Wlinc + (n * 16 + ln) * HH + kk * 32 + q * 8);
            acc[n] = mfma16(a, bf, acc[n]);
        }
    }

    float bl[16];
    #pragma unroll
    for (int n = 0; n < 16; ++n) bl[n] = blin[n * 16 + ln];

    #pragma unroll
    for (int reg = 0; reg < 4; ++reg) {
        float v[16];
        float mx = -3.4e38f;
        #pragma unroll
        for (int n = 0; n < 16; ++n) {
            v[n] = acc[n][reg] + bl[n];
            mx = fmaxf(mx, v[n]);
        }
        #pragma unroll
        for (int m = 1; m < 16; m <<= 1) mx = fmaxf(mx, __shfl_xor(mx, m));
        float sum = 0.0f;
        #pragma unroll
        for (int n = 0; n < 16; ++n) { v[n] = __expf(v[n] - mx); sum += v[n]; }
        #pragma unroll
        for (int m = 1; m < 16; m <<= 1) sum += __shfl_xor(sum, m);
        const float inv = 1.0f / sum;

        const int r = r0 + q * 4 + reg;        // r = b*T + t
        #pragma unroll
        for (int n = 0; n < 16; ++n)
            out[(size_t)r * VV + n * 16 + ln] = v[n] * inv;
    }
}

extern "C" void kernel_launch(void* const* d_in, const int* in_sizes, int n_in,
                              void* d_out, int out_size, void* d_ws, size_t ws_size,
                              hipStream_t stream)
{
    const float* x     = (const float*)d_in[0];
    const float* W_ih1 = (const float*)d_in[1];
    const float* W_hh1 = (const float*)d_in[2];
    const float* b_ih1 = (const float*)d_in[3];
    const float* b_hh1 = (const float*)d_in[4];
    const float* W_ih2 = (const float*)d_in[5];
    const float* W_hh2 = (const float*)d_in[6];
    const float* b_ih2 = (const float*)d_in[7];
    const float* b_hh2 = (const float*)d_in[8];
    const float* W_lin = (const float*)d_in[9];
    const float* b_lin = (const float*)d_in[10];

    char* p = (char*)d_ws;
    unsigned* flags  = (unsigned*)p;   p += 16384;                    // 4 x 4KB lines
    unsigned* h1all  = (unsigned*)p;   p += (size_t)1025 * 131072;    // 128.1 MB
    const size_t zbytes = 16384 + 131072;                             // flags + h1 slot 0
    float* bsum1 = (float*)p;          p += 2048 * 4;
    float* bsum2 = (float*)p;          p += 2048 * 4;
    float* xT    = (float*)p;          p += (size_t)BB * TT * 4;
    __hip_bfloat16* Whh1c = (__hip_bfloat16*)p; p += (size_t)2048 * 512 * 2;
    __hip_bfloat16* Wih2c = (__hip_bfloat16*)p; p += (size_t)2048 * 512 * 2;
    __hip_bfloat16* Whh2c = (__hip_bfloat16*)p; p += (size_t)2048 * 512 * 2;
    __hip_bfloat16* Wlinc = (__hip_bfloat16*)p; p += (size_t)256 * 512 * 2;
    // total ws use ~141 MB (proven available)

    hipMemsetAsync(d_ws, 0, zbytes, stream);   // flags + h1 slot 0

    canon<<<dim3(512), dim3(256), 0, stream>>>(
        x, W_hh1, W_ih2, W_hh2, W_lin, b_ih1, b_hh1, b_ih2, b_hh2,
        Whh1c, Wih2c, Whh2c, Wlinc, bsum1, bsum2, xT);

    const int smem_bytes = 131072;   // 128 KB dynamic LDS
    (void)hipFuncSetAttribute((const void*)lstm_persist,
                              hipFuncAttributeMaxDynamicSharedMemorySize, smem_bytes);

    lstm_persist<<<dim3(NBLK), dim3(256), smem_bytes, stream>>>(
        xT, W_ih1, Whh1c, bsum1, Wih2c, Whh2c, bsum2,
        flags, h1all, (__hip_bfloat16*)d_out);

    lin_softmax<<<dim3((TT * BB) / 64), dim3(256), 0, stream>>>(
        Wlinc, b_lin, (float*)d_out);
}

// Round 6
// 8560.008 us; speedup vs baseline: 1.1290x; 1.0786x over previous
//
#include <hip/hip_runtime.h>
#include <hip/hip_bf16.h>

// Problem constants
#define BB 128   // batch
#define TT 1024  // timesteps
#define HH 512   // hidden
#define VV 256   // vocab
#define NBLK 128 // 64 stage1 + 64 stage2 blocks (32 per batch-half each) — proven co-resident

typedef __attribute__((ext_vector_type(8))) short short8;   // 8 x bf16
typedef __attribute__((ext_vector_type(4))) float floatx4;  // MFMA acc

__device__ __forceinline__ floatx4 mfma16(short8 a, short8 b, floatx4 c) {
    return __builtin_amdgcn_mfma_f32_16x16x32_bf16(a, b, c, 0, 0, 0);
}
__device__ __forceinline__ float sigm(float x) { return 1.0f / (1.0f + __expf(-x)); }
__device__ __forceinline__ float tanh_fast(float x) {
    return 2.0f / (1.0f + __expf(-2.0f * x)) - 1.0f;
}
__device__ __forceinline__ void vmcnt0() {
    asm volatile("s_waitcnt vmcnt(0)" ::: "memory");
}
// waitcnt + scheduler fence: MFMAs consuming asm-load results must not hoist above.
__device__ __forceinline__ void vm_fence() {
    asm volatile("s_waitcnt vmcnt(0)" ::: "memory");
    __builtin_amdgcn_sched_barrier(0);
}
// Relaxed agent-scope ops: MALL-coherent, NO cache writeback/invalidate.
__device__ __forceinline__ unsigned ald32(const unsigned* p) {
    return __hip_atomic_load(p, __ATOMIC_RELAXED, __HIP_MEMORY_SCOPE_AGENT);
}
__device__ __forceinline__ void ast32(unsigned* p, unsigned v) {
    __hip_atomic_store(p, v, __ATOMIC_RELAXED, __HIP_MEMORY_SCOPE_AGENT);
}
// MALL-path 16B load (bypasses local caches) for reused ring addresses.
__device__ __forceinline__ short8 ld16_sc1(const __hip_bfloat16* p) {
    short8 v;
    asm volatile("global_load_dwordx4 %0, %1, off sc1" : "=v"(v) : "v"(p));
    return v;
}

// Spin until all 32 flags of `line` >= tgt (lanes 0-31 poll; coalesced 1-line load).
// Callable per-wave (each calling wave polls independently).
__device__ __forceinline__ void poll1(const unsigned* line, unsigned tgt, int lane) {
    for (;;) {
        unsigned v = tgt;
        if (lane < 32) v = ald32(line + lane);
        if (__all((int)(v >= tgt))) return;
        __builtin_amdgcn_s_sleep(1);
    }
}

// One-shot canonicalization: fp32 weights -> bf16 ws copies; bias pre-sums; x transpose.
__global__ __launch_bounds__(256) void canon(
    const float* __restrict__ x,
    const float* __restrict__ Whh1, const float* __restrict__ Wih2,
    const float* __restrict__ Whh2, const float* __restrict__ Wlin,
    const float* __restrict__ bih1, const float* __restrict__ bhh1,
    const float* __restrict__ bih2, const float* __restrict__ bhh2,
    __hip_bfloat16* __restrict__ Whh1c, __hip_bfloat16* __restrict__ Wih2c,
    __hip_bfloat16* __restrict__ Whh2c, __hip_bfloat16* __restrict__ Wlinc,
    float* __restrict__ bsum1, float* __restrict__ bsum2,
    float* __restrict__ xT)
{
    const int tid = blockIdx.x * 256 + threadIdx.x;
    const int np  = gridDim.x * 256;
    for (int i = tid; i < 2048 * 512; i += np) {
        Whh1c[i] = __float2bfloat16(Whh1[i]);
        Wih2c[i] = __float2bfloat16(Wih2[i]);
        Whh2c[i] = __float2bfloat16(Whh2[i]);
    }
    for (int i = tid; i < 256 * 512; i += np) Wlinc[i] = __float2bfloat16(Wlin[i]);
    for (int i = tid; i < 2048; i += np) {
        bsum1[i] = bih1[i] + bhh1[i];
        bsum2[i] = bih2[i] + bhh2[i];
    }
    for (int i = tid; i < BB * TT; i += np) {
        int b = i >> 10, t = i & 1023;
        xT[t * BB + b] = x[i];
    }
}

// Persistent dataflow LSTM. 4 independent groups: {stage1,stage2} x {batch half}.
// Sync (R3-proven core): flag lines spread 4 KB apart; flags[line*1024+lb] =
// completed steps of block lb. S1 publishes to TWO lines: line1 (own-group
// recurrence; polled only by S1 wave 0s) and line1c (consumer copy; checked by
// S2 waves) -> the line S1's own recurrence depends on is uncontended by S2.
// S2 step split: feed-forward part (check line1c, load h1(t), 64 MFMA) runs
// BEFORE the recurrent wait (wave-0 poll line2 + barrier); only the h2-dependent
// half (A1 loads, 64 MFMA, epilogue, ring store, drain, flag) is serial.
// h1: full array (slot t+1 = h1(t)), agent stores, plain loads. h2: 4-deep sc1
// ring (compact, MALL-resident); d_out stores post-publish, fire-and-forget.
__global__ __launch_bounds__(256, 1) void lstm_persist(
    const float* __restrict__ xT,              // [T][B] fp32
    const float* __restrict__ Wih1,            // [2048] fp32 (IN=1)
    const __hip_bfloat16* __restrict__ Whh1c,  // [2048,512] bf16
    const float* __restrict__ bsum1,           // [2048]
    const __hip_bfloat16* __restrict__ Wih2c,  // [2048,512] bf16
    const __hip_bfloat16* __restrict__ Whh2c,  // [2048,512] bf16
    const float* __restrict__ bsum2,           // [2048]
    unsigned* __restrict__ flags,              // [6][1024] u32, 4KB-strided lines
    unsigned* __restrict__ h1all,              // [1025][B*H/2] u32
    unsigned* __restrict__ h2ring,             // [4][B*H/2] u32
    __hip_bfloat16* __restrict__ h2slots)      // d_out as bf16 slots [B][T][H]
{
    extern __shared__ __hip_bfloat16 lds[];    // stage1: 64 KB; stage2: 128 KB

    const int bid   = blockIdx.x;
    const int stage = bid >> 6;                // 0: layer1, 1: layer2
    const int half  = (bid >> 5) & 1;          // batch half
    const int lb    = bid & 31;
    const int j0    = lb * 16;                 // h-unit tile
    const int b0    = half * 64;               // batch tile
    const int w     = threadIdx.x >> 6;
    const int lane  = threadIdx.x & 63;
    const int q     = lane >> 4, ln = lane & 15;
    const int r0    = b0 + w * 16;

    unsigned* line1  = flags + half * 1024;          // stage1 own-group line
    unsigned* line2  = flags + (2 + half) * 1024;    // stage2 own-group line
    unsigned* line1c = flags + (4 + half) * 1024;    // stage1 consumer copy
    unsigned* myflag  = (stage == 0) ? (line1 + lb) : (line2 + lb);
    unsigned* myflagc = line1c + lb;                 // used by stage1 only

    // ---- stage weights into LDS, fragment-permuted (once) ----
    {
        const __hip_bfloat16* S0 = (stage == 0) ? Whh1c : Wih2c;
        for (int idx = threadIdx.x; idx < 4096; idx += 256) {
            const int g = idx >> 10, kk = (idx >> 6) & 15, l = idx & 63;
            const int lnt = l & 15, qt = l >> 4;
            const size_t src = (size_t)(g * 512 + j0 + lnt) * 512 + kk * 32 + qt * 8;
            *(float4*)(lds + idx * 8) = *(const float4*)(S0 + src);
            if (stage == 1)
                *(float4*)(lds + 32768 + idx * 8) = *(const float4*)(Whh2c + src);
        }
    }
    __syncthreads();   // weights ready

    // per-thread step-invariant epilogue constants
    float wv[4], bs[4];
    #pragma unroll
    for (int g = 0; g < 4; ++g) {
        const int j = g * 512 + j0 + ln;
        if (stage == 0) { wv[g] = Wih1[j]; bs[g] = bsum1[j]; }
        else            { wv[g] = 0.0f;    bs[g] = bsum2[j]; }
    }
    float cre[4] = {0.0f, 0.0f, 0.0f, 0.0f};   // register-resident cell state

    const __hip_bfloat16* h1bf = (const __hip_bfloat16*)h1all;
    const int aoff = (r0 + ln) * HH + q * 8;          // A-frag element offset
    const int jc   = j0 + (ln & ~1);                  // pack: even column of pair
    const int rA   = (ln & 1) ? 2 : 0;
    const int bA   = r0 + q * 4 + rA;
    const int o0   = (bA * HH + jc) >> 1;
    const int o1   = ((bA + 1) * HH + jc) >> 1;

    for (int t = 0; t < TT; ++t) {
        floatx4 acc[4];
        #pragma unroll
        for (int g = 0; g < 4; ++g) acc[g] = floatx4{0, 0, 0, 0};
        unsigned pk[4];

        if (stage == 0) {
            if (w == 0 && t > 0) poll1(line1, (unsigned)t, lane);  // own group done t-1
            __syncthreads();                                       // release all waves
            // h1(t-1) = slot t, plain cached dwordx4 loads (unique addresses)
            const __hip_bfloat16* hA = h1bf + (size_t)t * 65536;
            float4 xv4 = *(const float4*)(xT + t * BB + r0 + q * 4);
            short8 A0[16];
            #pragma unroll
            for (int kk = 0; kk < 16; ++kk)
                A0[kk] = *(const short8*)(hA + aoff + kk * 32);
            #pragma unroll
            for (int kk = 0; kk < 16; ++kk) {
                #pragma unroll
                for (int g = 0; g < 4; ++g)
                    acc[g] = mfma16(A0[kk],
                        *(const short8*)(lds + ((g * 16 + kk) * 64 + lane) * 8), acc[g]);
            }
            #pragma unroll
            for (int reg = 0; reg < 4; ++reg) {
                const float xv = ((const float*)&xv4)[reg];
                float gi = acc[0][reg] + xv * wv[0] + bs[0];
                float gf = acc[1][reg] + xv * wv[1] + bs[1];
                float gg = acc[2][reg] + xv * wv[2] + bs[2];
                float go = acc[3][reg] + xv * wv[3] + bs[3];
                float cn = sigm(gf) * cre[reg] + sigm(gi) * tanh_fast(gg);
                cre[reg] = cn;
                float hn = sigm(go) * tanh_fast(cn);
                __hip_bfloat16 hb = __float2bfloat16(hn);
                unsigned short us; __builtin_memcpy(&us, &hb, 2);
                unsigned mine = us;
                unsigned other = (unsigned)__shfl_xor((int)mine, 1, 64);
                pk[reg] = (ln & 1) ? ((other & 0xffffu) | (mine << 16))
                                   : ((mine & 0xffffu) | (other << 16));
            }
            unsigned* dst = h1all + (size_t)(t + 1) * 32768;    // h1(t) -> slot t+1
            ast32(dst + o0, pk[rA]);
            ast32(dst + o1, pk[rA + 1]);
            // publish: drain stores, converge, dual flag store (own + consumer)
            vmcnt0();
            __syncthreads();
            if (threadIdx.x == 0) {
                ast32(myflag,  (unsigned)(t + 1));
                ast32(myflagc, (unsigned)(t + 1));
            }
        } else {
            // ---- feed-forward half: h1(t) (S1 runs ahead; check usually instant)
            poll1(line1c, (unsigned)(t + 1), lane);    // per-wave, no barrier
            asm volatile("" ::: "memory");             // keep loads below the poll
            const __hip_bfloat16* hA = h1bf + (size_t)(t + 1) * 65536;
            short8 A0[16];
            #pragma unroll
            for (int kk = 0; kk < 16; ++kk)
                A0[kk] = *(const short8*)(hA + aoff + kk * 32);
            #pragma unroll
            for (int kk = 0; kk < 16; ++kk) {
                #pragma unroll
                for (int g = 0; g < 4; ++g)
                    acc[g] = mfma16(A0[kk],
                        *(const short8*)(lds + ((g * 16 + kk) * 64 + lane) * 8), acc[g]);
            }
            // ---- recurrent half: h2(t-1)
            if (w == 0 && t > 0) poll1(line2, (unsigned)t, lane);
            __syncthreads();                           // release all waves
            if (t > 0) {
                const __hip_bfloat16* hB =
                    (const __hip_bfloat16*)h2ring + (size_t)(t & 3) * 65536;
                short8 A1[16];
                #pragma unroll
                for (int kk = 0; kk < 16; ++kk) A1[kk] = ld16_sc1(hB + aoff + kk * 32);
                vm_fence();   // A1 resident
                #pragma unroll
                for (int kk = 0; kk < 16; ++kk) {
                    #pragma unroll
                    for (int g = 0; g < 4; ++g)
                        acc[g] = mfma16(A1[kk],
                            *(const short8*)(lds + 32768 + ((g * 16 + kk) * 64 + lane) * 8), acc[g]);
                }
            }
            #pragma unroll
            for (int reg = 0; reg < 4; ++reg) {
                float gi = acc[0][reg] + bs[0];
                float gf = acc[1][reg] + bs[1];
                float gg = acc[2][reg] + bs[2];
                float go = acc[3][reg] + bs[3];
                float cn = sigm(gf) * cre[reg] + sigm(gi) * tanh_fast(gg);
                cre[reg] = cn;
                float hn = sigm(go) * tanh_fast(cn);
                __hip_bfloat16 hb = __float2bfloat16(hn);
                unsigned short us; __builtin_memcpy(&us, &hb, 2);
                unsigned mine = us;
                unsigned other = (unsigned)__shfl_xor((int)mine, 1, 64);
                pk[reg] = (ln & 1) ? ((other & 0xffffu) | (mine << 16))
                                   : ((mine & 0xffffu) | (other << 16));
            }
            // recurrence-critical ring stores, drain, converge, flag
            unsigned* dst = h2ring + (size_t)((t + 1) & 3) * 32768; // h2(t)
            ast32(dst + o0, pk[rA]);
            ast32(dst + o1, pk[rA + 1]);
            vmcnt0();
            __syncthreads();
            if (threadIdx.x == 0) ast32(myflag, (unsigned)(t + 1));
            // output stores post-publish: fire-and-forget (drained next iter /
            // at kernel end; unique addresses, plain cached)
            unsigned* outs = (unsigned*)h2slots;
            outs[(((size_t)bA * TT + t) * HH + jc) >> 1]       = pk[rA];
            outs[(((size_t)(bA + 1) * TT + t) * HH + jc) >> 1] = pk[rA + 1];
        }
    }
}

// In-place linear+softmax over all T*B rows (slot r: 512 bf16 -> 256 fp32).
__global__ __launch_bounds__(256) void lin_softmax(
    const __hip_bfloat16* __restrict__ Wlinc,  // [256,512] bf16
    const float* __restrict__ blin,            // [256] fp32
    float* out)                                // d_out; aliases the bf16 slots
{
    const __hip_bfloat16* slots = (const __hip_bfloat16*)out;
    const int w = threadIdx.x >> 6;
    const int lane = threadIdx.x & 63;
    const int q = lane >> 4, ln = lane & 15;
    const int r0 = blockIdx.x * 64 + w * 16;

    floatx4 acc[16];
    #pragma unroll
    for (int n = 0; n < 16; ++n) acc[n] = floatx4{0, 0, 0, 0};

    const size_t arow = (size_t)(r0 + ln) * HH + q * 8;
    #pragma unroll 4
    for (int kk = 0; kk < 16; ++kk) {
        short8 a = *(const short8*)(slots + arow + kk * 32);
        #pragma unroll
        for (int n = 0; n < 16; ++n) {
            short8 bf = *(const short8*)(Wlinc + (n * 16 + ln) * HH + kk * 32 + q * 8);
            acc[n] = mfma16(a, bf, acc[n]);
        }
    }

    float bl[16];
    #pragma unroll
    for (int n = 0; n < 16; ++n) bl[n] = blin[n * 16 + ln];

    #pragma unroll
    for (int reg = 0; reg < 4; ++reg) {
        float v[16];
        float mx = -3.4e38f;
        #pragma unroll
        for (int n = 0; n < 16; ++n) {
            v[n] = acc[n][reg] + bl[n];
            mx = fmaxf(mx, v[n]);
        }
        #pragma unroll
        for (int m = 1; m < 16; m <<= 1) mx = fmaxf(mx, __shfl_xor(mx, m));
        float sum = 0.0f;
        #pragma unroll
        for (int n = 0; n < 16; ++n) { v[n] = __expf(v[n] - mx); sum += v[n]; }
        #pragma unroll
        for (int m = 1; m < 16; m <<= 1) sum += __shfl_xor(sum, m);
        const float inv = 1.0f / sum;

        const int r = r0 + q * 4 + reg;        // r = b*T + t
        #pragma unroll
        for (int n = 0; n < 16; ++n)
            out[(size_t)r * VV + n * 16 + ln] = v[n] * inv;
    }
}

extern "C" void kernel_launch(void* const* d_in, const int* in_sizes, int n_in,
                              void* d_out, int out_size, void* d_ws, size_t ws_size,
                              hipStream_t stream)
{
    const float* x     = (const float*)d_in[0];
    const float* W_ih1 = (const float*)d_in[1];
    const float* W_hh1 = (const float*)d_in[2];
    const float* b_ih1 = (const float*)d_in[3];
    const float* b_hh1 = (const float*)d_in[4];
    const float* W_ih2 = (const float*)d_in[5];
    const float* W_hh2 = (const float*)d_in[6];
    const float* b_ih2 = (const float*)d_in[7];
    const float* b_hh2 = (const float*)d_in[8];
    const float* W_lin = (const float*)d_in[9];
    const float* b_lin = (const float*)d_in[10];

    char* p = (char*)d_ws;
    unsigned* flags  = (unsigned*)p;   p += 24576;                    // 6 x 4KB lines
    unsigned* h1all  = (unsigned*)p;   p += (size_t)1025 * 131072;    // 128.1 MB
    const size_t zbytes = 24576 + 131072;                             // flags + h1 slot 0
    unsigned* h2ring = (unsigned*)p;   p += (size_t)4 * 131072;       // 512 KB
    float* bsum1 = (float*)p;          p += 2048 * 4;
    float* bsum2 = (float*)p;          p += 2048 * 4;
    float* xT    = (float*)p;          p += (size_t)BB * TT * 4;
    __hip_bfloat16* Whh1c = (__hip_bfloat16*)p; p += (size_t)2048 * 512 * 2;
    __hip_bfloat16* Wih2c = (__hip_bfloat16*)p; p += (size_t)2048 * 512 * 2;
    __hip_bfloat16* Whh2c = (__hip_bfloat16*)p; p += (size_t)2048 * 512 * 2;
    __hip_bfloat16* Wlinc = (__hip_bfloat16*)p; p += (size_t)256 * 512 * 2;
    // total ws use ~142 MB (proven available)

    hipMemsetAsync(d_ws, 0, zbytes, stream);   // flags + h1 slot 0 (ring not needed: t=0 skips A1)

    canon<<<dim3(512), dim3(256), 0, stream>>>(
        x, W_hh1, W_ih2, W_hh2, W_lin, b_ih1, b_hh1, b_ih2, b_hh2,
        Whh1c, Wih2c, Whh2c, Wlinc, bsum1, bsum2, xT);

    const int smem_bytes = 131072;   // 128 KB dynamic LDS
    (void)hipFuncSetAttribute((const void*)lstm_persist,
                              hipFuncAttributeMaxDynamicSharedMemorySize, smem_bytes);

    lstm_persist<<<dim3(NBLK), dim3(256), smem_bytes, stream>>>(
        xT, W_ih1, Whh1c, bsum1, Wih2c, Whh2c, bsum2,
        flags, h1all, h2ring, (__hip_bfloat16*)d_out);

    lin_softmax<<<dim3((TT * BB) / 64), dim3(256), 0, stream>>>(
        Wlinc, b_lin, (float*)d_out);
}